// Round 1
// baseline (414.019 us; speedup 1.0000x reference)
//
#include <hip/hip_runtime.h>
#include <stdint.h>

#define NNODES 100000
#define NEDGES 100000
#define DIM    256
#define NCH    4          // 2 side + 2 rel
#define ET     64         // edges per block

typedef short bf16x8 __attribute__((ext_vector_type(8)));
typedef float f32x4  __attribute__((ext_vector_type(4)));

__device__ __forceinline__ short f2bf_rn(float x) {
    union { float f; uint32_t u; } v; v.f = x;
    uint32_t u = v.u;
    uint32_t r = u + 0x7fffu + ((u >> 16) & 1u);
    return (short)(r >> 16);
}
__device__ __forceinline__ float bf2f(short s) {
    union { float f; uint32_t u; } v;
    v.u = ((uint32_t)(unsigned short)s) << 16;
    return v.f;
}

// ---------------------------------------------------------------------------
// Prep: build the 4 fused/transposed matrices Mt[c][k][f] = M_c[f][k] in
// MFMA B-fragment-swizzled order, split into hi/lo bf16.
//   M_c[f][k] = d_side[c][f]*R_W[f][k]*d_side[c][k]   (c < 2)
//             = W_rel[c-2][f][k]                       (c >= 2)
// Fragment order: idx = (((c*8 + kc)*16 + ft)*64 + lane)*8 + j
//   where k = kc*32 + (lane>>4)*8 + j, f = ft*16 + (lane&15)
// One thread per (c,kc,ft,lane); 4*8*16*64 = 32768 threads.
// ---------------------------------------------------------------------------
__global__ void prep_B(const float* __restrict__ RW,
                       const float* __restrict__ dside,
                       const float* __restrict__ Wrel,
                       short* __restrict__ Bh, short* __restrict__ Bl) {
    int t = blockIdx.x * blockDim.x + threadIdx.x;
    if (t >= NCH * 8 * 16 * 64) return;
    int lane = t & 63;
    int ft   = (t >> 6) & 15;
    int kc   = (t >> 10) & 7;
    int c    = t >> 13;
    int quad = lane >> 4, col = lane & 15;
    int f     = ft * 16 + col;
    int kbase = kc * 32 + quad * 8;

    bf16x8 vh, vl;
#pragma unroll
    for (int j = 0; j < 8; ++j) {
        int k = kbase + j;
        float val;
        if (c < 2) {
            val = dside[c * DIM + f] * RW[f * DIM + k] * dside[c * DIM + k];
        } else {
            val = Wrel[(size_t)(c - 2) * DIM * DIM + f * DIM + k];
        }
        short hi = f2bf_rn(val);
        float rem = val - bf2f(hi);
        vh[j] = hi;
        vl[j] = f2bf_rn(rem);
    }
    ((bf16x8*)Bh)[t] = vh;
    ((bf16x8*)Bl)[t] = vl;
}

// ---------------------------------------------------------------------------
// Fused edge kernel: per (channel, 64-edge tile):
//   C(64x256) = gathered U(64x256) @ Mt (split-bf16, 3 MFMA terms)
//   score[e]  = sum_f (C[e][f] + bias[f]) * V[e][f]
// Block = 256 threads = 4 waves; wave w owns f-range [w*64, w*64+64),
// all 64 edges (4 m-tiles of 16). acc[mt][ft] = 4x4 f32x4 = 64 regs.
// ---------------------------------------------------------------------------
__global__ __launch_bounds__(256, 2)
void edge_kernel(const float* __restrict__ hmat,
                 const int* __restrict__ src_idx,
                 const int* __restrict__ dst_idx,
                 const float* __restrict__ brel,
                 const short* __restrict__ Bh_sw,
                 const short* __restrict__ Bl_sw,
                 float* __restrict__ out) {
    const int c    = blockIdx.y;
    const int e0   = blockIdx.x * ET;
    const int tid  = threadIdx.x;
    const int w    = tid >> 6;
    const int lane = tid & 63;
    const int quad = lane >> 4, col = lane & 15;

    __shared__ uint32_t s_src[ET];
    __shared__ uint32_t s_dst[ET];
    __shared__ float    red[4][ET];

    if (tid < ET) {
        int ge = e0 + tid;
        int si = 0, di = 0;
        if (ge < NEDGES) {
            si = src_idx[(size_t)c * NEDGES + ge];
            di = dst_idx[(size_t)c * NEDGES + ge];
        }
        s_src[tid] = (uint32_t)si;
        s_dst[tid] = (uint32_t)di;
    }
    __syncthreads();

    f32x4 acc[4][4];
#pragma unroll
    for (int i = 0; i < 4; ++i)
#pragma unroll
        for (int j = 0; j < 4; ++j) acc[i][j] = (f32x4){0.f, 0.f, 0.f, 0.f};

    // Hoist per-lane A-row base pointers (A row m = col within each m-tile).
    const float* baseu[4];
#pragma unroll
    for (int mt = 0; mt < 4; ++mt)
        baseu[mt] = hmat + (size_t)s_src[mt * 16 + col] * DIM;

    const bf16x8* Bh = (const bf16x8*)Bh_sw;
    const bf16x8* Bl = (const bf16x8*)Bl_sw;

#pragma unroll
    for (int kc = 0; kc < 8; ++kc) {
        // Gather + split-convert A fragments: lane holds U[e=mt*16+col][k..k+7]
        bf16x8 Ah[4], Al[4];
#pragma unroll
        for (int mt = 0; mt < 4; ++mt) {
            const f32x4* p4 = (const f32x4*)(baseu[mt] + kc * 32 + quad * 8);
            f32x4 x0 = p4[0];
            f32x4 x1 = p4[1];
            bf16x8 ah, al;
#pragma unroll
            for (int j = 0; j < 4; ++j) {
                short hi = f2bf_rn(x0[j]);
                ah[j] = hi;
                al[j] = f2bf_rn(x0[j] - bf2f(hi));
            }
#pragma unroll
            for (int j = 0; j < 4; ++j) {
                short hi = f2bf_rn(x1[j]);
                ah[4 + j] = hi;
                al[4 + j] = f2bf_rn(x1[j] - bf2f(hi));
            }
            Ah[mt] = ah;
            Al[mt] = al;
        }
        // B fragments from pre-swizzled global (L2-resident), 3-term split MFMA
        int fb = ((c * 8 + kc) * 16 + w * 4) * 64 + lane;
#pragma unroll
        for (int ft = 0; ft < 4; ++ft) {
            bf16x8 bh = Bh[fb + ft * 64];
            bf16x8 bl = Bl[fb + ft * 64];
#pragma unroll
            for (int mt = 0; mt < 4; ++mt) {
                acc[mt][ft] = __builtin_amdgcn_mfma_f32_16x16x32_bf16(Ah[mt], bh, acc[mt][ft], 0, 0, 0);
                acc[mt][ft] = __builtin_amdgcn_mfma_f32_16x16x32_bf16(Ah[mt], bl, acc[mt][ft], 0, 0, 0);
                acc[mt][ft] = __builtin_amdgcn_mfma_f32_16x16x32_bf16(Al[mt], bh, acc[mt][ft], 0, 0, 0);
            }
        }
    }

    // Epilogue: score_e = sum_f (C[e][f] + bias[f]) * V[e][f]
    // C/D layout: col = lane&15 (f), row = quad*4 + reg (e within m-tile).
    float psum[4][4];  // [mt][r]
#pragma unroll
    for (int mt = 0; mt < 4; ++mt)
#pragma unroll
        for (int r = 0; r < 4; ++r) psum[mt][r] = 0.f;

#pragma unroll
    for (int ft = 0; ft < 4; ++ft) {
        int f = w * 64 + ft * 16 + col;
        float bias = 0.f;
        if (c >= 2) bias = brel[(size_t)(c - 2) * DIM + f];
#pragma unroll
        for (int mt = 0; mt < 4; ++mt) {
#pragma unroll
            for (int r = 0; r < 4; ++r) {
                int el = mt * 16 + quad * 4 + r;
                float v = hmat[(size_t)s_dst[el] * DIM + f];
                psum[mt][r] += (acc[mt][ft][r] + bias) * v;
            }
        }
    }

    // Reduce across the 16 f-columns (lanes within quad: xor bits 0..3)
#pragma unroll
    for (int off = 1; off < 16; off <<= 1) {
#pragma unroll
        for (int mt = 0; mt < 4; ++mt)
#pragma unroll
            for (int r = 0; r < 4; ++r)
                psum[mt][r] += __shfl_xor(psum[mt][r], off, 64);
    }
    if (col == 0) {
#pragma unroll
        for (int mt = 0; mt < 4; ++mt)
#pragma unroll
            for (int r = 0; r < 4; ++r)
                red[w][mt * 16 + quad * 4 + r] = psum[mt][r];
    }
    __syncthreads();

    // Sum the 4 per-wave f-range partials, write scores
    if (tid < ET) {
        int ge = e0 + tid;
        if (ge < NEDGES) {
            float s = red[0][tid] + red[1][tid] + red[2][tid] + red[3][tid];
            out[(size_t)c * NEDGES + ge] = s;
        }
    }
}

extern "C" void kernel_launch(void* const* d_in, const int* in_sizes, int n_in,
                              void* d_out, int out_size, void* d_ws, size_t ws_size,
                              hipStream_t stream) {
    const float* hmat  = (const float*)d_in[0];
    const int*   src   = (const int*)d_in[1];
    const int*   dst   = (const int*)d_in[2];
    const float* RW    = (const float*)d_in[3];
    const float* dside = (const float*)d_in[4];
    const float* Wrel  = (const float*)d_in[5];
    const float* brel  = (const float*)d_in[6];
    float* out = (float*)d_out;

    // Workspace: two swizzled bf16 tables, 4*256*256 elements each (512 KB each)
    short* Bh = (short*)d_ws;
    short* Bl = Bh + (size_t)NCH * DIM * DIM;

    prep_B<<<dim3((NCH * 8 * 16 * 64) / 256), dim3(256), 0, stream>>>(RW, dside, Wrel, Bh, Bl);

    dim3 grid((NEDGES + ET - 1) / ET, NCH);
    edge_kernel<<<grid, dim3(256), 0, stream>>>(hmat, src, dst, brel, Bh, Bl, out);
}